// Round 4
// baseline (546.050 us; speedup 1.0000x reference)
//
#include <hip/hip_runtime.h>
#include <hip/hip_bf16.h>
#include <stdint.h>

typedef __bf16 bf16x8 __attribute__((ext_vector_type(8)));
typedef float f32x4 __attribute__((ext_vector_type(4)));
typedef unsigned short u16;
typedef unsigned int u32;

#define DEVI __device__ __forceinline__

DEVI u16 f2b(float f){ __bf16 h = (__bf16)f; return __builtin_bit_cast(u16, h); }
DEVI float b2f(u16 u){ return (float)__builtin_bit_cast(__bf16, u); }

constexpr int BSZ = 2, SEQ = 2048, DIM = 2048, NH = 16, HD = 128;

#if defined(__has_builtin)
#if __has_builtin(__builtin_amdgcn_global_load_lds)
#define HAVE_ASYNC_LDS 1
#endif
#endif

DEVI void cp16(void* lds, const void* g){
#ifdef HAVE_ASYNC_LDS
  auto gp = (const __attribute__((address_space(1))) u32*)(uintptr_t)g;
  auto lp = (__attribute__((address_space(3))) u32*)(uintptr_t)lds;
  __builtin_amdgcn_global_load_lds(gp, lp, 16, 0, 0);
#else
  *(uint4*)lds = *(const uint4*)g;
#endif
}

// ---------------------------------------------------------------- convert
__global__ __launch_bounds__(256) void k_convert(
    const float* __restrict__ x, const float* __restrict__ wq,
    const float* __restrict__ wk, const float* __restrict__ wv,
    const float* __restrict__ wo,
    u16* __restrict__ xb, u16* __restrict__ wqkv, u16* __restrict__ wob)
{
  int e = (blockIdx.x * 256 + threadIdx.x) * 4;
  float4 v; u16* dp;
  if (e < 8388608){
    v = *(const float4*)&x[e]; dp = &xb[e];
  } else if (e < 20971520){
    int o = e - 8388608; int sec = o >> 22; int oo = o & 4194303;
    const float* w = (sec == 0) ? wq : ((sec == 1) ? wk : wv);
    v = *(const float4*)&w[oo]; dp = &wqkv[o];
  } else {
    int o = e - 20971520;
    v = *(const float4*)&wo[o]; dp = &wob[o];
  }
  ushort4 r; r.x = f2b(v.x); r.y = f2b(v.y); r.z = f2b(v.z); r.w = f2b(v.w);
  *(ushort4*)dp = r;
}

// ---------------------------------------------------------------- 256x128 GEMM core
DEVI void gemm_core_256x128(u16* smem, const u16* __restrict__ A, const u16* __restrict__ B,
                            int tm, int tn, int t, f32x4 (&acc)[4][4])
{
  const int lane = t & 63, l15 = lane & 15, quad = lane >> 4;
  const int wave = t >> 6, wm = wave >> 1, wn = wave & 1;
  const int swr = (l15 & 7) << 3;                 // read-side XOR (u16 units)
  const int rb = t >> 3;
  const int csw = ((t & 7) ^ (rb & 7)) << 3;      // inverse-swizzled source slot
  const u16* As0 = A + (size_t)(tm + rb) * DIM + csw;
  const u16* Bs0 = B + (size_t)(tn + rb) * DIM + csw;

  auto STAGE = [&](int kt){
    const int buf = kt & 1;
    const int kb = kt * 64;
    u16* d = &smem[buf * 24576 + t * 8];
    #pragma unroll
    for (int p = 0; p < 4; ++p)                   // A: 256 rows in 4 passes of 64
      cp16(d + p * 4096, As0 + (size_t)p * (64 * DIM) + kb);
    #pragma unroll
    for (int p = 0; p < 2; ++p)                   // B: 128 rows in 2 passes
      cp16(d + 16384 + p * 4096, Bs0 + (size_t)p * (64 * DIM) + kb);
  };

  STAGE(0);
  #pragma unroll 2
  for (int kt = 0; kt < DIM / 64; ++kt){
    __syncthreads();                              // drains prev-tile loads (old) + barrier
    if (kt < DIM / 64 - 1) STAGE(kt + 1);         // prefetch into other buffer
    const u16* Ab = &smem[(kt & 1) * 24576];
    const u16* Bb = Ab + 16384;
    bf16x8 Af[4][2], Bf[4][2];
    #pragma unroll
    for (int mt = 0; mt < 4; ++mt)
      #pragma unroll
      for (int ks = 0; ks < 2; ++ks)
        Af[mt][ks] = *(const bf16x8*)&Ab[(wm * 64 + mt * 16 + l15) * 64 + ((ks * 32 + quad * 8) ^ swr)];
    #pragma unroll
    for (int nt = 0; nt < 4; ++nt)
      #pragma unroll
      for (int ks = 0; ks < 2; ++ks)
        Bf[nt][ks] = *(const bf16x8*)&Bb[(wn * 64 + nt * 16 + l15) * 64 + ((ks * 32 + quad * 8) ^ swr)];
    #pragma unroll
    for (int c = 0; c < 4; ++c){                  // 4 clusters of 8 MFMA (T5)
      const int mb = (c >> 1) * 2, nb = (c & 1) * 2;
      __builtin_amdgcn_s_setprio(1);
      #pragma unroll
      for (int mi = 0; mi < 2; ++mi)
        #pragma unroll
        for (int ni = 0; ni < 2; ++ni)
          #pragma unroll
          for (int ks = 0; ks < 2; ++ks)
            acc[mb + mi][nb + ni] = __builtin_amdgcn_mfma_f32_16x16x32_bf16(
                Af[mb + mi][ks], Bf[nb + ni][ks], acc[mb + mi][nb + ni], 0, 0, 0);
      __builtin_amdgcn_s_setprio(0);
    }
  }
  __syncthreads();
}

// ---------------------------------------------------------------- gemm QKV (+fused RoPE epilogue)
__global__ __launch_bounds__(512, 2) void k_gemm_qkv(
    const u16* __restrict__ A, const u16* __restrict__ W,
    const float* __restrict__ fc, const float* __restrict__ fs,
    u16* __restrict__ Qd, u16* __restrict__ Kd, u16* __restrict__ Vd)
{
  __shared__ __align__(16) u16 smem[49152];       // 96 KB buffers; reused as Cs
  const int t = threadIdx.x;
  const int wg = blockIdx.x;
  const int id = (wg & 7) * 96 + (wg >> 3);       // T1: 768 wgs, 8 XCDs, bijective
  const int tm = (id & 15) << 8;                  // 16 M-tiles of 256
  const int tn = (id >> 4) << 7;                  // 48 N-tiles of 128 (one head each)
  f32x4 acc[4][4] = {};
  gemm_core_256x128(smem, A, W, tm, tn, t, acc);

  const int lane = t & 63, l15 = lane & 15, quad = lane >> 4;
  const int wave = t >> 6, wm = wave >> 1, wn = wave & 1;
  u16* Cs = smem;                                 // [256][128] u16 = 64 KB
  #pragma unroll
  for (int mt = 0; mt < 4; ++mt)
    #pragma unroll
    for (int nt = 0; nt < 4; ++nt)
      #pragma unroll
      for (int r = 0; r < 4; ++r){
        int rin = wm * 64 + mt * 16 + quad * 4 + r;
        int col = wn * 64 + nt * 16 + l15;
        Cs[rin * 128 + ((col + rin * 8) & 127)] = f2b(acc[mt][nt][r]);
      }
  __syncthreads();

  const int sec = tn >> 11;
  const int hh = (tn & 2047) >> 7;
  u16* dst = (sec == 0) ? Qd : ((sec == 1) ? Kd : Vd);
  const float qs = (sec == 0) ? (0.08838834764831845f * 1.4426950408889634f) : 1.0f;
  const int col0 = (t & 15) * 8;
  #pragma unroll
  for (int jj = 0; jj < 8; ++jj){
    int row = (t >> 4) + jj * 32;
    int m = tm + row;
    int b = m >> 11, s = m & 2047;
    uint4 cv = *(const uint4*)&Cs[row * 128 + ((col0 + row * 8) & 127)];
    const u16* cp = (const u16*)&cv;
    u16 op[8];
    if (sec < 2){
      float4 c4 = *(const float4*)&fc[(size_t)s * 64 + (col0 >> 1)];
      float4 s4 = *(const float4*)&fs[(size_t)s * 64 + (col0 >> 1)];
      float cc[4] = {c4.x*qs, c4.y*qs, c4.z*qs, c4.w*qs};
      float ss[4] = {s4.x*qs, s4.y*qs, s4.z*qs, s4.w*qs};
      #pragma unroll
      for (int p = 0; p < 4; ++p){
        float a = b2f(cp[2*p]), bb = b2f(cp[2*p+1]);
        op[2*p]   = f2b(a*cc[p] - bb*ss[p]);
        op[2*p+1] = f2b(a*ss[p] + bb*cc[p]);
      }
    } else {
      #pragma unroll
      for (int p = 0; p < 8; ++p) op[p] = cp[p];
    }
    *(uint4*)&dst[((size_t)(b*NH + hh)*SEQ + s)*HD + col0] = *(const uint4*)op;
  }
}

// ---------------------------------------------------------------- V transpose
__global__ __launch_bounds__(256) void k_vtrans(
    const u16* __restrict__ V, u16* __restrict__ Vt)
{
  __shared__ u16 ts[64*72];
  const int t = threadIdx.x;
  const int st = blockIdx.x, dt = blockIdx.y, bh = blockIdx.z;
  const size_t base  = (size_t)bh * SEQ * HD;
  const size_t baseT = (size_t)bh * HD * SEQ;
  #pragma unroll
  for (int i = 0; i < 2; ++i){
    int s = i*32 + (t>>3), c = t&7;
    *(uint4*)&ts[s*72 + c*8] = *(const uint4*)&V[base + (size_t)(st*64 + s)*HD + dt*64 + c*8];
  }
  __syncthreads();
  #pragma unroll
  for (int i = 0; i < 2; ++i){
    int d = i*32 + (t>>3), sc = t&7;
    u16 tmp[8];
    #pragma unroll
    for (int j = 0; j < 8; ++j) tmp[j] = ts[(sc*8 + j)*72 + d];
    *(uint4*)&Vt[baseT + (size_t)(dt*64 + d)*SEQ + st*64 + sc*8] = *(const uint4*)tmp;
  }
}

// ---------------------------------------------------------------- flash attention
// 512 threads, 8 waves x 16 q-rows (BM=128, BN=64), split-K=2.
// Grid 512 flat: xcd = flat&7, 4 heads per XCD -> that head-group's K/V
// (4 MB) is L2-resident (r3 measured FETCH=30MB). Therefore: NO LDS
// staging of K/V at all -- MFMA operand fragments are loaded directly
// from global (L1/L2 serve them). ZERO __syncthreads: LDS holds only
// per-wave-private P and O-transpose regions, waves run fully
// independently (max TLP to hide L2 latency). Each wave clamps its
// k-loop to its own causal bound.
__global__ __launch_bounds__(512) void k_flash(
    const u16* __restrict__ Qd, const u16* __restrict__ Kd,
    const u16* __restrict__ Vt, u16* __restrict__ OP0, u16* __restrict__ OP1,
    float* __restrict__ Mp, float* __restrict__ Lp)
{
  __shared__ __align__(16) u16 lds[24576];  // 8x Ps[16][64] (16KB) | 8x Osw[16][128] (32KB)
  const int t = threadIdx.x, lane = t & 63, wave = t >> 6;
  const int l15 = lane & 15, quad = lane >> 4;
  const int swz = (l15 & 7) << 3;

  const int flat = blockIdx.x;
  const int xcd = flat & 7, idx = flat >> 3;
  const int bh = xcd * 4 + (idx >> 4);      // 4 heads per XCD
  const int x = idx & 15;
  const int b = bh >> 4, h = bh & 15;
  const int j = x >> 1, split = x & 1;

  const size_t base  = (size_t)bh * SEQ * HD;
  const size_t baseT = (size_t)bh * HD * SEQ;
  u16* Psw = lds + wave * 1024;             // per-wave P [16][64], swizzled
  u16* Osw = lds + 8192 + wave * 2048;      // per-wave O [16][128], swizzled
  u16* OPs = split ? OP1 : OP0;
  const int lo = 17*split, hi = lo + 17;
  const int qt0 = j, qt1 = 15 - j;
  const int len0 = 2*qt0 + 2;

  for (int pass = 0; pass < 2; ++pass){
    const int qt = pass ? qt1 : qt0;
    const int len = 2*qt + 2;
    int kt0 = pass ? (lo - len0) : lo; if (kt0 < 0) kt0 = 0;
    int kt1 = pass ? (hi - len0) : hi; if (kt1 > len) kt1 = len;
    const int qb = qt*128 + wave*16;
    const int ktw = min(kt1, ((qb + 15) >> 6) + 1);   // per-wave causal clamp

    bf16x8 qf[4];
    #pragma unroll
    for (int ks = 0; ks < 4; ++ks)
      qf[ks] = *(const bf16x8*)&Qd[base + (size_t)(qb + l15)*HD + ks*32 + quad*8];

    f32x4 oacc[8] = {};
    float m_s = -1e30f, l_s = 0.f;

    for (int kt = kt0; kt < ktw; ++kt){
      // ---- QK^T: K fragments straight from L1/L2
      f32x4 sacc[4] = {};
      #pragma unroll
      for (int ks = 0; ks < 4; ++ks){
        bf16x8 kf[4];
        #pragma unroll
        for (int nk = 0; nk < 4; ++nk)
          kf[nk] = *(const bf16x8*)&Kd[base + (size_t)(kt*64 + nk*16 + l15)*HD + ks*32 + quad*8];
        __builtin_amdgcn_s_setprio(1);
        #pragma unroll
        for (int nk = 0; nk < 4; ++nk)
          sacc[nk] = __builtin_amdgcn_mfma_f32_16x16x32_bf16(kf[nk], qf[ks], sacc[nk], 0, 0, 0);
        __builtin_amdgcn_s_setprio(0);
      }
      if (kt*64 + 63 > qb){         // diagonal tile only: apply causal mask
        int q = qb + l15;
        #pragma unroll
        for (int nk = 0; nk < 4; ++nk)
          #pragma unroll
          for (int r = 0; r < 4; ++r){
            int key = kt*64 + nk*16 + quad*4 + r;
            if (key > q) sacc[nk][r] = -1e30f;
          }
      }
      // online softmax (tree reductions, 2 cross-quad shuffles each)
      float m4[4];
      #pragma unroll
      for (int nk = 0; nk < 4; ++nk)
        m4[nk] = fmaxf(fmaxf(sacc[nk][0], sacc[nk][1]), fmaxf(sacc[nk][2], sacc[nk][3]));
      float rm = fmaxf(fmaxf(m4[0], m4[1]), fmaxf(m4[2], m4[3]));
      rm = fmaxf(rm, __shfl_xor(rm, 16));
      rm = fmaxf(rm, __shfl_xor(rm, 32));
      float mnew = fmaxf(m_s, rm);
      float alpha = exp2f(m_s - mnew);
      m_s = mnew;
      float s4[4];
      #pragma unroll
      for (int nk = 0; nk < 4; ++nk){
        u16 pk[4];
        float p0 = exp2f(sacc[nk][0] - mnew);
        float p1 = exp2f(sacc[nk][1] - mnew);
        float p2 = exp2f(sacc[nk][2] - mnew);
        float p3 = exp2f(sacc[nk][3] - mnew);
        pk[0] = f2b(p0); pk[1] = f2b(p1); pk[2] = f2b(p2); pk[3] = f2b(p3);
        s4[nk] = (p0 + p1) + (p2 + p3);
        *(uint2*)&Psw[l15*64 + ((nk*16 + quad*4) ^ swz)] = *(const uint2*)pk;
      }
      float rs = (s4[0] + s4[1]) + (s4[2] + s4[3]);
      rs += __shfl_xor(rs, 16);
      rs += __shfl_xor(rs, 32);
      l_s = l_s*alpha + rs;
      #pragma unroll
      for (int db = 0; db < 8; ++db)
        #pragma unroll
        for (int r = 0; r < 4; ++r) oacc[db][r] *= alpha;
      // ---- O^T += V^T.P^T : V fragments straight from L1/L2
      #pragma unroll
      for (int k2 = 0; k2 < 2; ++k2){
        bf16x8 pf = *(const bf16x8*)&Psw[l15*64 + ((k2*32 + quad*8) ^ swz)];
        bf16x8 vf[8];
        #pragma unroll
        for (int db = 0; db < 8; ++db)
          vf[db] = *(const bf16x8*)&Vt[baseT + (size_t)(db*16 + l15)*SEQ + kt*64 + k2*32 + quad*8];
        __builtin_amdgcn_s_setprio(1);
        #pragma unroll
        for (int db = 0; db < 8; ++db)
          oacc[db] = __builtin_amdgcn_mfma_f32_16x16x32_bf16(vf[db], pf, oacc[db], 0, 0, 0);
        __builtin_amdgcn_s_setprio(0);
      }
    }
    // epilogue: transpose O^T -> O rows via per-wave LDS, coalesced stores
    {
      #pragma unroll
      for (int db = 0; db < 8; ++db){
        u16 ok[4];
        #pragma unroll
        for (int r = 0; r < 4; ++r) ok[r] = f2b(oacc[db][r]);
        *(uint2*)&Osw[l15*128 + ((db*16 + quad*4) ^ swz)] = *(const uint2*)ok;
      }
      #pragma unroll
      for (int i = 0; i < 4; ++i){
        int q = i*4 + quad;
        uint4 v = *(const uint4*)&Osw[q*128 + ((l15*8) ^ ((q & 7) << 3))];
        *(uint4*)&OPs[(((size_t)(b*SEQ + qb + q))*NH + h)*HD + l15*8] = v;
      }
      if (quad == 0){
        size_t mi = ((size_t)split*BSZ*NH + bh)*SEQ + (qb + l15);
        Mp[mi] = m_s;
        Lp[mi] = l_s;
      }
    }
  }
}

// ---------------------------------------------------------------- combine splits (in-place into OP0)
__global__ __launch_bounds__(256) void k_combine(
    u16* __restrict__ OP0, const u16* __restrict__ OP1,
    const float* __restrict__ Mp, const float* __restrict__ Lp)
{
  size_t flat = ((size_t)blockIdx.x*256 + threadIdx.x)*8;
  int h = (int)((flat >> 7) & 15);
  int s = (int)((flat >> 11) & 2047);
  int b = (int)(flat >> 22);
  size_t row = ((size_t)(b*NH + h))*SEQ + s;
  const size_t off1 = (size_t)BSZ*NH*SEQ;
  float m0 = Mp[row], l0 = Lp[row];
  float m1 = Mp[row + off1], l1 = Lp[row + off1];
  float m = fmaxf(m0, m1);
  float w0 = exp2f(m0 - m), w1 = exp2f(m1 - m);
  float inv = 1.0f / (w0*l0 + w1*l1);
  uint4 a = *(const uint4*)&OP0[flat];
  uint4 c = *(const uint4*)&OP1[flat];
  const u16* pa = (const u16*)&a;
  const u16* pc = (const u16*)&c;
  u16 o[8];
  #pragma unroll
  for (int i = 0; i < 8; ++i)
    o[i] = f2b((b2f(pa[i])*w0 + b2f(pc[i])*w1) * inv);
  *(uint4*)&OP0[flat] = *(const uint4*)o;
}

// ---------------------------------------------------------------- out proj
__global__ __launch_bounds__(512, 2) void k_gemm_out(
    const u16* __restrict__ A, const u16* __restrict__ W, float* __restrict__ out)
{
  __shared__ __align__(16) u16 smem[49152];
  const int t = threadIdx.x;
  const int wg = blockIdx.x;
  const int id = (wg & 7) * 32 + (wg >> 3);   // 256 wgs, 8 XCDs, bijective
  const int tm = (id & 15) << 8;              // 16 M-tiles of 256
  const int tn = (id >> 4) << 7;              // 16 N-tiles of 128
  f32x4 acc[4][4] = {};
  gemm_core_256x128(smem, A, W, tm, tn, t, acc);
  const int lane = t & 63, l15 = lane & 15, quad = lane >> 4;
  const int wave = t >> 6, wm = wave >> 1, wn = wave & 1;
  #pragma unroll
  for (int mt = 0; mt < 4; ++mt)
    #pragma unroll
    for (int nt = 0; nt < 4; ++nt)
      #pragma unroll
      for (int r = 0; r < 4; ++r){
        int row = tm + wm*64 + mt*16 + quad*4 + r;
        int col = tn + wn*64 + nt*16 + l15;
        out[(size_t)row*DIM + col] = acc[mt][nt][r];
      }
}

// ---------------------------------------------------------------- launch
extern "C" void kernel_launch(void* const* d_in, const int* in_sizes, int n_in,
                              void* d_out, int out_size, void* d_ws, size_t ws_size,
                              hipStream_t stream)
{
  const float* x  = (const float*)d_in[0];
  const float* wq = (const float*)d_in[1];
  const float* wk = (const float*)d_in[2];
  const float* wv = (const float*)d_in[3];
  const float* wo = (const float*)d_in[4];
  const float* fc = (const float*)d_in[5];
  const float* fs = (const float*)d_in[6];
  float* out = (float*)d_out;

  char* ws = (char*)d_ws;
  u16* xb   = (u16*)(ws);                 // 16 MB  bf16 x; aliased as Vt after gemm_qkv
  u16* wqkv = (u16*)(ws + 16777216);      // 24 MB; aliased as OP1 + M/L after gemm_qkv
  u16* wob  = (u16*)(ws + 41943040);      //  8 MB
  u16* Qr   = (u16*)(ws + 50331648);      // 16 MB  (B,NH,S,HD)
  u16* Kr   = (u16*)(ws + 67108864);      // 16 MB
  u16* Vr   = (u16*)(ws + 83886080);      // 16 MB
  u16* Ob   = (u16*)(ws + 100663296);     // 16 MB  (B,S,NH,HD): split0 partial, then combined
  u16* VtT  = xb;
  u16* OP1  = wqkv;                       // 16 MB split1 partial
  float* Mp = (float*)(ws + 33554432);    // 512 KB [split][bh][s]
  float* Lp = (float*)(ws + 34078720);    // 512 KB

  k_convert <<<24576, 256, 0, stream>>>(x, wq, wk, wv, wo, xb, wqkv, wob);
  k_gemm_qkv<<<768, 512, 0, stream>>>(xb, wqkv, fc, fs, Qr, Kr, Vr);
  k_vtrans  <<<dim3(32, 2, 32), 256, 0, stream>>>(Vr, VtT);
  k_flash   <<<512, 512, 0, stream>>>(Qr, Kr, VtT, Ob, OP1, Mp, Lp);
  k_combine <<<4096, 256, 0, stream>>>(Ob, OP1, Mp, Lp);
  k_gemm_out<<<256, 512, 0, stream>>>(Ob, wob, out);
}

// Round 5
// 439.670 us; speedup vs baseline: 1.2420x; 1.2420x over previous
//
#include <hip/hip_runtime.h>
#include <hip/hip_bf16.h>
#include <stdint.h>

typedef __bf16 bf16x8 __attribute__((ext_vector_type(8)));
typedef float f32x4 __attribute__((ext_vector_type(4)));
typedef unsigned short u16;
typedef unsigned int u32;

#define DEVI __device__ __forceinline__

DEVI u16 f2b(float f){ __bf16 h = (__bf16)f; return __builtin_bit_cast(u16, h); }
DEVI float b2f(u16 u){ return (float)__builtin_bit_cast(__bf16, u); }

constexpr int BSZ = 2, SEQ = 2048, DIM = 2048, NH = 16, HD = 128;

#if defined(__has_builtin)
#if __has_builtin(__builtin_amdgcn_global_load_lds)
#define HAVE_ASYNC_LDS 1
#endif
#endif

DEVI void cp16(void* lds, const void* g){
#ifdef HAVE_ASYNC_LDS
  auto gp = (const __attribute__((address_space(1))) u32*)(uintptr_t)g;
  auto lp = (__attribute__((address_space(3))) u32*)(uintptr_t)lds;
  __builtin_amdgcn_global_load_lds(gp, lp, 16, 0, 0);
#else
  *(uint4*)lds = *(const uint4*)g;
#endif
}

// ---------------------------------------------------------------- convert
__global__ __launch_bounds__(256) void k_convert(
    const float* __restrict__ x, const float* __restrict__ wq,
    const float* __restrict__ wk, const float* __restrict__ wv,
    const float* __restrict__ wo,
    u16* __restrict__ xb, u16* __restrict__ wqkv, u16* __restrict__ wob)
{
  int e = (blockIdx.x * 256 + threadIdx.x) * 4;
  float4 v; u16* dp;
  if (e < 8388608){
    v = *(const float4*)&x[e]; dp = &xb[e];
  } else if (e < 20971520){
    int o = e - 8388608; int sec = o >> 22; int oo = o & 4194303;
    const float* w = (sec == 0) ? wq : ((sec == 1) ? wk : wv);
    v = *(const float4*)&w[oo]; dp = &wqkv[o];
  } else {
    int o = e - 20971520;
    v = *(const float4*)&wo[o]; dp = &wob[o];
  }
  ushort4 r; r.x = f2b(v.x); r.y = f2b(v.y); r.z = f2b(v.z); r.w = f2b(v.w);
  *(ushort4*)dp = r;
}

// ---------------------------------------------------------------- 256x128 GEMM core
DEVI void gemm_core_256x128(u16* smem, const u16* __restrict__ A, const u16* __restrict__ B,
                            int tm, int tn, int t, f32x4 (&acc)[4][4])
{
  const int lane = t & 63, l15 = lane & 15, quad = lane >> 4;
  const int wave = t >> 6, wm = wave >> 1, wn = wave & 1;
  const int swr = (l15 & 7) << 3;                 // read-side XOR (u16 units)
  const int rb = t >> 3;
  const int csw = ((t & 7) ^ (rb & 7)) << 3;      // inverse-swizzled source slot
  const u16* As0 = A + (size_t)(tm + rb) * DIM + csw;
  const u16* Bs0 = B + (size_t)(tn + rb) * DIM + csw;

  auto STAGE = [&](int kt){
    const int buf = kt & 1;
    const int kb = kt * 64;
    u16* d = &smem[buf * 24576 + t * 8];
    #pragma unroll
    for (int p = 0; p < 4; ++p)                   // A: 256 rows in 4 passes of 64
      cp16(d + p * 4096, As0 + (size_t)p * (64 * DIM) + kb);
    #pragma unroll
    for (int p = 0; p < 2; ++p)                   // B: 128 rows in 2 passes
      cp16(d + 16384 + p * 4096, Bs0 + (size_t)p * (64 * DIM) + kb);
  };

  STAGE(0);
  #pragma unroll 2
  for (int kt = 0; kt < DIM / 64; ++kt){
    __syncthreads();                              // drains prev-tile loads (old) + barrier
    if (kt < DIM / 64 - 1) STAGE(kt + 1);         // prefetch into other buffer
    const u16* Ab = &smem[(kt & 1) * 24576];
    const u16* Bb = Ab + 16384;
    bf16x8 Af[4][2], Bf[4][2];
    #pragma unroll
    for (int mt = 0; mt < 4; ++mt)
      #pragma unroll
      for (int ks = 0; ks < 2; ++ks)
        Af[mt][ks] = *(const bf16x8*)&Ab[(wm * 64 + mt * 16 + l15) * 64 + ((ks * 32 + quad * 8) ^ swr)];
    #pragma unroll
    for (int nt = 0; nt < 4; ++nt)
      #pragma unroll
      for (int ks = 0; ks < 2; ++ks)
        Bf[nt][ks] = *(const bf16x8*)&Bb[(wn * 64 + nt * 16 + l15) * 64 + ((ks * 32 + quad * 8) ^ swr)];
    #pragma unroll
    for (int c = 0; c < 4; ++c){                  // 4 clusters of 8 MFMA (T5)
      const int mb = (c >> 1) * 2, nb = (c & 1) * 2;
      __builtin_amdgcn_s_setprio(1);
      #pragma unroll
      for (int mi = 0; mi < 2; ++mi)
        #pragma unroll
        for (int ni = 0; ni < 2; ++ni)
          #pragma unroll
          for (int ks = 0; ks < 2; ++ks)
            acc[mb + mi][nb + ni] = __builtin_amdgcn_mfma_f32_16x16x32_bf16(
                Af[mb + mi][ks], Bf[nb + ni][ks], acc[mb + mi][nb + ni], 0, 0, 0);
      __builtin_amdgcn_s_setprio(0);
    }
  }
  __syncthreads();
}

// ---------------------------------------------------------------- gemm QKV (+fused RoPE epilogue)
__global__ __launch_bounds__(512, 2) void k_gemm_qkv(
    const u16* __restrict__ A, const u16* __restrict__ W,
    const float* __restrict__ fc, const float* __restrict__ fs,
    u16* __restrict__ Qd, u16* __restrict__ Kd, u16* __restrict__ Vd)
{
  __shared__ __align__(16) u16 smem[49152];       // 96 KB buffers; reused as Cs
  const int t = threadIdx.x;
  const int wg = blockIdx.x;
  const int id = (wg & 7) * 96 + (wg >> 3);       // T1: 768 wgs, 8 XCDs, bijective
  const int tm = (id & 15) << 8;                  // 16 M-tiles of 256
  const int tn = (id >> 4) << 7;                  // 48 N-tiles of 128 (one head each)
  f32x4 acc[4][4] = {};
  gemm_core_256x128(smem, A, W, tm, tn, t, acc);

  const int lane = t & 63, l15 = lane & 15, quad = lane >> 4;
  const int wave = t >> 6, wm = wave >> 1, wn = wave & 1;
  u16* Cs = smem;                                 // [256][128] u16 = 64 KB
  #pragma unroll
  for (int mt = 0; mt < 4; ++mt)
    #pragma unroll
    for (int nt = 0; nt < 4; ++nt)
      #pragma unroll
      for (int r = 0; r < 4; ++r){
        int rin = wm * 64 + mt * 16 + quad * 4 + r;
        int col = wn * 64 + nt * 16 + l15;
        Cs[rin * 128 + ((col + rin * 8) & 127)] = f2b(acc[mt][nt][r]);
      }
  __syncthreads();

  const int sec = tn >> 11;
  const int hh = (tn & 2047) >> 7;
  u16* dst = (sec == 0) ? Qd : ((sec == 1) ? Kd : Vd);
  const float qs = (sec == 0) ? (0.08838834764831845f * 1.4426950408889634f) : 1.0f;
  const int col0 = (t & 15) * 8;
  #pragma unroll
  for (int jj = 0; jj < 8; ++jj){
    int row = (t >> 4) + jj * 32;
    int m = tm + row;
    int b = m >> 11, s = m & 2047;
    uint4 cv = *(const uint4*)&Cs[row * 128 + ((col0 + row * 8) & 127)];
    const u16* cp = (const u16*)&cv;
    u16 op[8];
    if (sec < 2){
      float4 c4 = *(const float4*)&fc[(size_t)s * 64 + (col0 >> 1)];
      float4 s4 = *(const float4*)&fs[(size_t)s * 64 + (col0 >> 1)];
      float cc[4] = {c4.x*qs, c4.y*qs, c4.z*qs, c4.w*qs};
      float ss[4] = {s4.x*qs, s4.y*qs, s4.z*qs, s4.w*qs};
      #pragma unroll
      for (int p = 0; p < 4; ++p){
        float a = b2f(cp[2*p]), bb = b2f(cp[2*p+1]);
        op[2*p]   = f2b(a*cc[p] - bb*ss[p]);
        op[2*p+1] = f2b(a*ss[p] + bb*cc[p]);
      }
    } else {
      #pragma unroll
      for (int p = 0; p < 8; ++p) op[p] = cp[p];
    }
    *(uint4*)&dst[((size_t)(b*NH + hh)*SEQ + s)*HD + col0] = *(const uint4*)op;
  }
}

// ---------------------------------------------------------------- V transpose
__global__ __launch_bounds__(256) void k_vtrans(
    const u16* __restrict__ V, u16* __restrict__ Vt)
{
  __shared__ u16 ts[64*72];
  const int t = threadIdx.x;
  const int st = blockIdx.x, dt = blockIdx.y, bh = blockIdx.z;
  const size_t base  = (size_t)bh * SEQ * HD;
  const size_t baseT = (size_t)bh * HD * SEQ;
  #pragma unroll
  for (int i = 0; i < 2; ++i){
    int s = i*32 + (t>>3), c = t&7;
    *(uint4*)&ts[s*72 + c*8] = *(const uint4*)&V[base + (size_t)(st*64 + s)*HD + dt*64 + c*8];
  }
  __syncthreads();
  #pragma unroll
  for (int i = 0; i < 2; ++i){
    int d = i*32 + (t>>3), sc = t&7;
    u16 tmp[8];
    #pragma unroll
    for (int j = 0; j < 8; ++j) tmp[j] = ts[(sc*8 + j)*72 + d];
    *(uint4*)&Vt[baseT + (size_t)(dt*64 + d)*SEQ + st*64 + sc*8] = *(const uint4*)tmp;
  }
}

// ---------------------------------------------------------------- flash attention
// 512 threads, 8 waves x 16 q-rows (BM=128, BN=64), split-K=2.
// Grid 512 flat: xcd = flat&7, 4 heads per XCD (L2-resident K/V).
// Double-buffered Ks/Vs (80 KB), ONE barrier per tile, vmcnt waits kept
// OUT of barrier-to-barrier sections:
//   compute(buf) -> write(buf^1) [stall overlaps other waves' compute]
//   -> issue load(kt+2) -> barrier.
// Safety: write(buf^1)@k vs reads@k-1 separated by barrier@k-1; vs
// reads@k+1 by barrier@k. Loop bounds block-uniform. Epilogue transposes
// O through the wave-PRIVATE Psw slice (2 chunks of 64 cols) -> no
// barriers; one barrier per pass boundary protects Ks/Vs reuse.
__global__ __launch_bounds__(512) void k_flash(
    const u16* __restrict__ Qd, const u16* __restrict__ Kd,
    const u16* __restrict__ Vt, u16* __restrict__ OP0, u16* __restrict__ OP1,
    float* __restrict__ Mp, float* __restrict__ Lp)
{
  __shared__ __align__(16) u16 lds[40960];  // Ks0|Ks1 (2x16KB) | Vs0|Vs1 (2x16KB) | Ps 8x2KB
  const int t = threadIdx.x, lane = t & 63, wave = t >> 6;
  const int l15 = lane & 15, quad = lane >> 4;
  const int swz = (l15 & 7) << 3;

  const int flat = blockIdx.x;
  const int xcd = flat & 7, idx = flat >> 3;
  const int bh = xcd * 4 + (idx >> 4);      // 4 heads per XCD
  const int x = idx & 15;
  const int b = bh >> 4, h = bh & 15;
  const int j = x >> 1, split = x & 1;

  const size_t base  = (size_t)bh * SEQ * HD;
  const size_t baseT = (size_t)bh * HD * SEQ;
  u16* Psw = lds + 32768 + wave * 1024;     // per-wave P [16][64], swizzled
  u16* OPs = split ? OP1 : OP0;
  const int lo = 17*split, hi = lo + 17;
  const int qt0 = j, qt1 = 15 - j;
  const int len0 = 2*qt0 + 2;

  const int krow = t >> 4, kslot = t & 15;  // K stage: rows +i*32
  const int vrow = t >> 3, vslot = t & 7;   // V stage: rows +i*64

  for (int pass = 0; pass < 2; ++pass){
    const int qt = pass ? qt1 : qt0;
    const int len = 2*qt + 2;
    int kt0 = pass ? (lo - len0) : lo; if (kt0 < 0) kt0 = 0;
    int kt1 = pass ? (hi - len0) : hi; if (kt1 > len) kt1 = len;
    const int qb = qt*128 + wave*16;

    bf16x8 qf[4];
    #pragma unroll
    for (int ks = 0; ks < 4; ++ks)
      qf[ks] = *(const bf16x8*)&Qd[base + (size_t)(qb + l15)*HD + ks*32 + quad*8];

    f32x4 oacc[8] = {};
    float m_s = -1e30f, l_s = 0.f;

    if (kt0 < kt1){
      uint4 kreg[2], vreg[2];
      auto LOADT = [&](int kt){
        #pragma unroll
        for (int i = 0; i < 2; ++i){
          kreg[i] = *(const uint4*)&Kd[base + (size_t)(kt*64 + i*32 + krow)*HD + kslot*8];
          vreg[i] = *(const uint4*)&Vt[baseT + (size_t)(i*64 + vrow)*SEQ + kt*64 + vslot*8];
        }
      };
      auto WRITET = [&](int bu){
        u16* Kb = lds + bu*8192;
        u16* Vb = lds + 16384 + bu*8192;
        #pragma unroll
        for (int i = 0; i < 2; ++i){
          int kr = i*32 + krow;
          *(uint4*)&Kb[kr*128 + ((kslot*8) ^ ((kr & 7) << 3))] = kreg[i];
          int vr = i*64 + vrow;
          *(uint4*)&Vb[vr*64 + ((vslot*8) ^ ((vr & 7) << 3))] = vreg[i];
        }
      };
      LOADT(kt0);
      WRITET(0);
      if (kt0 + 1 < kt1) LOADT(kt0 + 1);
      __syncthreads();
      int buf = 0;
      for (int kt = kt0; kt < kt1; ++kt){
        if (kt*64 <= qb + 15){          // wave-uniform: tile has visible keys
          const u16* Kb = lds + buf*8192;
          const u16* Vb = lds + 16384 + buf*8192;
          f32x4 sacc[4] = {};
          #pragma unroll
          for (int ks = 0; ks < 4; ++ks){
            bf16x8 kf[4];
            #pragma unroll
            for (int nk = 0; nk < 4; ++nk)
              kf[nk] = *(const bf16x8*)&Kb[(nk*16 + l15)*128 + ((ks*32 + quad*8) ^ swz)];
            __builtin_amdgcn_s_setprio(1);
            #pragma unroll
            for (int nk = 0; nk < 4; ++nk)
              sacc[nk] = __builtin_amdgcn_mfma_f32_16x16x32_bf16(kf[nk], qf[ks], sacc[nk], 0, 0, 0);
            __builtin_amdgcn_s_setprio(0);
          }
          if (kt*64 + 63 > qb){         // diagonal tile only: apply causal mask
            int q = qb + l15;
            #pragma unroll
            for (int nk = 0; nk < 4; ++nk)
              #pragma unroll
              for (int r = 0; r < 4; ++r){
                int key = kt*64 + nk*16 + quad*4 + r;
                if (key > q) sacc[nk][r] = -1e30f;
              }
          }
          // online softmax (tree reductions, 2 cross-quad shuffles each)
          float m4[4];
          #pragma unroll
          for (int nk = 0; nk < 4; ++nk)
            m4[nk] = fmaxf(fmaxf(sacc[nk][0], sacc[nk][1]), fmaxf(sacc[nk][2], sacc[nk][3]));
          float rm = fmaxf(fmaxf(m4[0], m4[1]), fmaxf(m4[2], m4[3]));
          rm = fmaxf(rm, __shfl_xor(rm, 16));
          rm = fmaxf(rm, __shfl_xor(rm, 32));
          float mnew = fmaxf(m_s, rm);
          float alpha = exp2f(m_s - mnew);
          m_s = mnew;
          float s4[4];
          #pragma unroll
          for (int nk = 0; nk < 4; ++nk){
            u16 pk[4];
            float p0 = exp2f(sacc[nk][0] - mnew);
            float p1 = exp2f(sacc[nk][1] - mnew);
            float p2 = exp2f(sacc[nk][2] - mnew);
            float p3 = exp2f(sacc[nk][3] - mnew);
            pk[0] = f2b(p0); pk[1] = f2b(p1); pk[2] = f2b(p2); pk[3] = f2b(p3);
            s4[nk] = (p0 + p1) + (p2 + p3);
            *(uint2*)&Psw[l15*64 + ((nk*16 + quad*4) ^ swz)] = *(const uint2*)pk;
          }
          float rs = (s4[0] + s4[1]) + (s4[2] + s4[3]);
          rs += __shfl_xor(rs, 16);
          rs += __shfl_xor(rs, 32);
          l_s = l_s*alpha + rs;
          #pragma unroll
          for (int db = 0; db < 8; ++db)
            #pragma unroll
            for (int r = 0; r < 4; ++r) oacc[db][r] *= alpha;
          // O^T += V^T . P^T
          #pragma unroll
          for (int k2 = 0; k2 < 2; ++k2){
            bf16x8 pf = *(const bf16x8*)&Psw[l15*64 + ((k2*32 + quad*8) ^ swz)];
            __builtin_amdgcn_s_setprio(1);
            #pragma unroll
            for (int db = 0; db < 8; ++db){
              bf16x8 vf = *(const bf16x8*)&Vb[(db*16 + l15)*64 + ((k2*32 + quad*8) ^ swz)];
              oacc[db] = __builtin_amdgcn_mfma_f32_16x16x32_bf16(vf, pf, oacc[db], 0, 0, 0);
            }
            __builtin_amdgcn_s_setprio(0);
          }
        }
        if (kt + 1 < kt1){
          WRITET(buf ^ 1);              // vmcnt stall overlaps other waves' compute
          if (kt + 2 < kt1) LOADT(kt + 2);
          __syncthreads();              // single barrier per tile
        }
        buf ^= 1;
      }
    }
    // epilogue: O^T -> O rows via wave-PRIVATE Psw slice, 2 chunks of 64 cols
    {
      u16* Ow = Psw;                    // [16][64], swizzled
      const int qrow = lane >> 2;
      #pragma unroll
      for (int ch = 0; ch < 2; ++ch){
        #pragma unroll
        for (int db2 = 0; db2 < 4; ++db2){
          int db = ch*4 + db2;
          u16 ok[4];
          #pragma unroll
          for (int r = 0; r < 4; ++r) ok[r] = f2b(oacc[db][r]);
          *(uint2*)&Ow[l15*64 + ((db2*16 + quad*4) ^ swz)] = *(const uint2*)ok;
        }
        #pragma unroll
        for (int i = 0; i < 2; ++i){
          int c8 = (lane & 3) + i*4;
          uint4 v = *(const uint4*)&Ow[qrow*64 + ((c8*8) ^ ((qrow & 7) << 3))];
          *(uint4*)&OPs[(((size_t)(b*SEQ + qb + qrow))*NH + h)*HD + ch*64 + c8*8] = v;
        }
      }
      if (quad == 0){
        size_t mi = ((size_t)split*BSZ*NH + bh)*SEQ + (qb + l15);
        Mp[mi] = m_s;
        Lp[mi] = l_s;
      }
    }
    __syncthreads();     // pass boundary: epilogue/compute done before next stage
  }
}

// ---------------------------------------------------------------- combine splits (in-place into OP0)
__global__ __launch_bounds__(256) void k_combine(
    u16* __restrict__ OP0, const u16* __restrict__ OP1,
    const float* __restrict__ Mp, const float* __restrict__ Lp)
{
  size_t flat = ((size_t)blockIdx.x*256 + threadIdx.x)*8;
  int h = (int)((flat >> 7) & 15);
  int s = (int)((flat >> 11) & 2047);
  int b = (int)(flat >> 22);
  size_t row = ((size_t)(b*NH + h))*SEQ + s;
  const size_t off1 = (size_t)BSZ*NH*SEQ;
  float m0 = Mp[row], l0 = Lp[row];
  float m1 = Mp[row + off1], l1 = Lp[row + off1];
  float m = fmaxf(m0, m1);
  float w0 = exp2f(m0 - m), w1 = exp2f(m1 - m);
  float inv = 1.0f / (w0*l0 + w1*l1);
  uint4 a = *(const uint4*)&OP0[flat];
  uint4 c = *(const uint4*)&OP1[flat];
  const u16* pa = (const u16*)&a;
  const u16* pc = (const u16*)&c;
  u16 o[8];
  #pragma unroll
  for (int i = 0; i < 8; ++i)
    o[i] = f2b((b2f(pa[i])*w0 + b2f(pc[i])*w1) * inv);
  *(uint4*)&OP0[flat] = *(const uint4*)o;
}

// ---------------------------------------------------------------- out proj
__global__ __launch_bounds__(512, 2) void k_gemm_out(
    const u16* __restrict__ A, const u16* __restrict__ W, float* __restrict__ out)
{
  __shared__ __align__(16) u16 smem[49152];
  const int t = threadIdx.x;
  const int wg = blockIdx.x;
  const int id = (wg & 7) * 32 + (wg >> 3);   // 256 wgs, 8 XCDs, bijective
  const int tm = (id & 15) << 8;              // 16 M-tiles of 256
  const int tn = (id >> 4) << 7;              // 16 N-tiles of 128
  f32x4 acc[4][4] = {};
  gemm_core_256x128(smem, A, W, tm, tn, t, acc);
  const int lane = t & 63, l15 = lane & 15, quad = lane >> 4;
  const int wave = t >> 6, wm = wave >> 1, wn = wave & 1;
  #pragma unroll
  for (int mt = 0; mt < 4; ++mt)
    #pragma unroll
    for (int nt = 0; nt < 4; ++nt)
      #pragma unroll
      for (int r = 0; r < 4; ++r){
        int row = tm + wm*64 + mt*16 + quad*4 + r;
        int col = tn + wn*64 + nt*16 + l15;
        out[(size_t)row*DIM + col] = acc[mt][nt][r];
      }
}

// ---------------------------------------------------------------- launch
extern "C" void kernel_launch(void* const* d_in, const int* in_sizes, int n_in,
                              void* d_out, int out_size, void* d_ws, size_t ws_size,
                              hipStream_t stream)
{
  const float* x  = (const float*)d_in[0];
  const float* wq = (const float*)d_in[1];
  const float* wk = (const float*)d_in[2];
  const float* wv = (const float*)d_in[3];
  const float* wo = (const float*)d_in[4];
  const float* fc = (const float*)d_in[5];
  const float* fs = (const float*)d_in[6];
  float* out = (float*)d_out;

  char* ws = (char*)d_ws;
  u16* xb   = (u16*)(ws);                 // 16 MB  bf16 x; aliased as Vt after gemm_qkv
  u16* wqkv = (u16*)(ws + 16777216);      // 24 MB; aliased as OP1 + M/L after gemm_qkv
  u16* wob  = (u16*)(ws + 41943040);      //  8 MB
  u16* Qr   = (u16*)(ws + 50331648);      // 16 MB  (B,NH,S,HD)
  u16* Kr   = (u16*)(ws + 67108864);      // 16 MB
  u16* Vr   = (u16*)(ws + 83886080);      // 16 MB
  u16* Ob   = (u16*)(ws + 100663296);     // 16 MB  (B,S,NH,HD): split0 partial, then combined
  u16* VtT  = xb;
  u16* OP1  = wqkv;                       // 16 MB split1 partial
  float* Mp = (float*)(ws + 33554432);    // 512 KB [split][bh][s]
  float* Lp = (float*)(ws + 34078720);    // 512 KB

  k_convert <<<24576, 256, 0, stream>>>(x, wq, wk, wv, wo, xb, wqkv, wob);
  k_gemm_qkv<<<768, 512, 0, stream>>>(xb, wqkv, fc, fs, Qr, Kr, Vr);
  k_vtrans  <<<dim3(32, 2, 32), 256, 0, stream>>>(Vr, VtT);
  k_flash   <<<512, 512, 0, stream>>>(Qr, Kr, VtT, Ob, OP1, Mp, Lp);
  k_combine <<<4096, 256, 0, stream>>>(Ob, OP1, Mp, Lp);
  k_gemm_out<<<256, 512, 0, stream>>>(Ob, wob, out);
}

// Round 6
// 429.754 us; speedup vs baseline: 1.2706x; 1.0231x over previous
//
#include <hip/hip_runtime.h>
#include <hip/hip_bf16.h>
#include <stdint.h>

typedef __bf16 bf16x8 __attribute__((ext_vector_type(8)));
typedef float f32x4 __attribute__((ext_vector_type(4)));
typedef unsigned short u16;
typedef unsigned int u32;

#define DEVI __device__ __forceinline__

DEVI u16 f2b(float f){ __bf16 h = (__bf16)f; return __builtin_bit_cast(u16, h); }
DEVI float b2f(u16 u){ return (float)__builtin_bit_cast(__bf16, u); }

constexpr int BSZ = 2, SEQ = 2048, DIM = 2048, NH = 16, HD = 128;

#if defined(__has_builtin)
#if __has_builtin(__builtin_amdgcn_global_load_lds)
#define HAVE_ASYNC_LDS 1
#endif
#endif

DEVI void cp16(void* lds, const void* g){
#ifdef HAVE_ASYNC_LDS
  auto gp = (const __attribute__((address_space(1))) u32*)(uintptr_t)g;
  auto lp = (__attribute__((address_space(3))) u32*)(uintptr_t)lds;
  __builtin_amdgcn_global_load_lds(gp, lp, 16, 0, 0);
#else
  *(uint4*)lds = *(const uint4*)g;
#endif
}

// ---------------------------------------------------------------- convert
__global__ __launch_bounds__(256) void k_convert(
    const float* __restrict__ x, const float* __restrict__ wq,
    const float* __restrict__ wk, const float* __restrict__ wv,
    const float* __restrict__ wo,
    u16* __restrict__ xb, u16* __restrict__ wqkv, u16* __restrict__ wob)
{
  int e = (blockIdx.x * 256 + threadIdx.x) * 4;
  float4 v; u16* dp;
  if (e < 8388608){
    v = *(const float4*)&x[e]; dp = &xb[e];
  } else if (e < 20971520){
    int o = e - 8388608; int sec = o >> 22; int oo = o & 4194303;
    const float* w = (sec == 0) ? wq : ((sec == 1) ? wk : wv);
    v = *(const float4*)&w[oo]; dp = &wqkv[o];
  } else {
    int o = e - 20971520;
    v = *(const float4*)&wo[o]; dp = &wob[o];
  }
  ushort4 r; r.x = f2b(v.x); r.y = f2b(v.y); r.z = f2b(v.z); r.w = f2b(v.w);
  *(ushort4*)dp = r;
}

// ---------------------------------------------------------------- 256x128 GEMM core
DEVI void gemm_core_256x128(u16* smem, const u16* __restrict__ A, const u16* __restrict__ B,
                            int tm, int tn, int t, f32x4 (&acc)[4][4])
{
  const int lane = t & 63, l15 = lane & 15, quad = lane >> 4;
  const int wave = t >> 6, wm = wave >> 1, wn = wave & 1;
  const int swr = (l15 & 7) << 3;                 // read-side XOR (u16 units)
  const int rb = t >> 3;
  const int csw = ((t & 7) ^ (rb & 7)) << 3;      // inverse-swizzled source slot
  const u16* As0 = A + (size_t)(tm + rb) * DIM + csw;
  const u16* Bs0 = B + (size_t)(tn + rb) * DIM + csw;

  auto STAGE = [&](int kt){
    const int buf = kt & 1;
    const int kb = kt * 64;
    u16* d = &smem[buf * 24576 + t * 8];
    #pragma unroll
    for (int p = 0; p < 4; ++p)                   // A: 256 rows in 4 passes of 64
      cp16(d + p * 4096, As0 + (size_t)p * (64 * DIM) + kb);
    #pragma unroll
    for (int p = 0; p < 2; ++p)                   // B: 128 rows in 2 passes
      cp16(d + 16384 + p * 4096, Bs0 + (size_t)p * (64 * DIM) + kb);
  };

  STAGE(0);
  #pragma unroll 2
  for (int kt = 0; kt < DIM / 64; ++kt){
    __syncthreads();                              // drains prev-tile loads (old) + barrier
    if (kt < DIM / 64 - 1) STAGE(kt + 1);         // prefetch into other buffer
    const u16* Ab = &smem[(kt & 1) * 24576];
    const u16* Bb = Ab + 16384;
    bf16x8 Af[4][2], Bf[4][2];
    #pragma unroll
    for (int mt = 0; mt < 4; ++mt)
      #pragma unroll
      for (int ks = 0; ks < 2; ++ks)
        Af[mt][ks] = *(const bf16x8*)&Ab[(wm * 64 + mt * 16 + l15) * 64 + ((ks * 32 + quad * 8) ^ swr)];
    #pragma unroll
    for (int nt = 0; nt < 4; ++nt)
      #pragma unroll
      for (int ks = 0; ks < 2; ++ks)
        Bf[nt][ks] = *(const bf16x8*)&Bb[(wn * 64 + nt * 16 + l15) * 64 + ((ks * 32 + quad * 8) ^ swr)];
    #pragma unroll
    for (int c = 0; c < 4; ++c){                  // 4 clusters of 8 MFMA (T5)
      const int mb = (c >> 1) * 2, nb = (c & 1) * 2;
      __builtin_amdgcn_s_setprio(1);
      #pragma unroll
      for (int mi = 0; mi < 2; ++mi)
        #pragma unroll
        for (int ni = 0; ni < 2; ++ni)
          #pragma unroll
          for (int ks = 0; ks < 2; ++ks)
            acc[mb + mi][nb + ni] = __builtin_amdgcn_mfma_f32_16x16x32_bf16(
                Af[mb + mi][ks], Bf[nb + ni][ks], acc[mb + mi][nb + ni], 0, 0, 0);
      __builtin_amdgcn_s_setprio(0);
    }
  }
  __syncthreads();
}

// ---------------------------------------------------------------- gemm QKV (+fused RoPE / V-transpose epilogue)
__global__ __launch_bounds__(512, 2) void k_gemm_qkv(
    const u16* __restrict__ A, const u16* __restrict__ W,
    const float* __restrict__ fc, const float* __restrict__ fs,
    u16* __restrict__ Qd, u16* __restrict__ Kd, u16* __restrict__ Vt)
{
  __shared__ __align__(16) u16 smem[49152];       // 96 KB buffers; reused as Cs
  const int t = threadIdx.x;
  const int wg = blockIdx.x;
  const int id = (wg & 7) * 96 + (wg >> 3);       // T1: 768 wgs, 8 XCDs, bijective
  const int tm = (id & 15) << 8;                  // 16 M-tiles of 256
  const int tn = (id >> 4) << 7;                  // 48 N-tiles of 128 (one head each)
  f32x4 acc[4][4] = {};
  gemm_core_256x128(smem, A, W, tm, tn, t, acc);

  const int lane = t & 63, l15 = lane & 15, quad = lane >> 4;
  const int wave = t >> 6, wm = wave >> 1, wn = wave & 1;
  u16* Cs = smem;                                 // [256][128] u16 = 64 KB
  #pragma unroll
  for (int mt = 0; mt < 4; ++mt)
    #pragma unroll
    for (int nt = 0; nt < 4; ++nt)
      #pragma unroll
      for (int r = 0; r < 4; ++r){
        int rin = wm * 64 + mt * 16 + quad * 4 + r;
        int col = wn * 64 + nt * 16 + l15;
        Cs[rin * 128 + ((col + rin * 8) & 127)] = f2b(acc[mt][nt][r]);
      }
  __syncthreads();

  const int sec = tn >> 11;
  const int hh = (tn & 2047) >> 7;
  if (sec < 2){
    // Q/K path: RoPE + row store
    u16* dst = (sec == 0) ? Qd : Kd;
    const float qs = (sec == 0) ? (0.08838834764831845f * 1.4426950408889634f) : 1.0f;
    const int col0 = (t & 15) * 8;
    #pragma unroll
    for (int jj = 0; jj < 8; ++jj){
      int row = (t >> 4) + jj * 32;
      int m = tm + row;
      int b = m >> 11, s = m & 2047;
      uint4 cv = *(const uint4*)&Cs[row * 128 + ((col0 + row * 8) & 127)];
      const u16* cp = (const u16*)&cv;
      u16 op[8];
      float4 c4 = *(const float4*)&fc[(size_t)s * 64 + (col0 >> 1)];
      float4 s4 = *(const float4*)&fs[(size_t)s * 64 + (col0 >> 1)];
      float cc[4] = {c4.x*qs, c4.y*qs, c4.z*qs, c4.w*qs};
      float ss[4] = {s4.x*qs, s4.y*qs, s4.z*qs, s4.w*qs};
      #pragma unroll
      for (int p = 0; p < 4; ++p){
        float a = b2f(cp[2*p]), bb = b2f(cp[2*p+1]);
        op[2*p]   = f2b(a*cc[p] - bb*ss[p]);
        op[2*p+1] = f2b(a*ss[p] + bb*cc[p]);
      }
      *(uint4*)&dst[((size_t)(b*NH + hh)*SEQ + s)*HD + col0] = *(const uint4*)op;
    }
  } else {
    // V path: fused transpose -> Vt[bh][d][s] (replaces k_vtrans)
    const int bb = tm >> 11;                      // 256-row tile never straddles batch
    const int sbase = tm & 2047;
    const size_t baseT = ((size_t)(bb*NH + hh)) * HD * SEQ;
    const int d0 = (t & 15) * 8;
    const int s0g = (t >> 4) * 8;
    u16 tr[8][8];
    #pragma unroll
    for (int jr = 0; jr < 8; ++jr){
      int row = s0g + jr;
      *(uint4*)&tr[jr][0] = *(const uint4*)&Cs[row * 128 + ((d0 + row * 8) & 127)];
    }
    #pragma unroll
    for (int jd = 0; jd < 8; ++jd){
      u16 o[8];
      #pragma unroll
      for (int jr = 0; jr < 8; ++jr) o[jr] = tr[jr][jd];
      *(uint4*)&Vt[baseT + (size_t)(d0 + jd)*SEQ + sbase + s0g] = *(const uint4*)o;
    }
  }
}

// ---------------------------------------------------------------- flash attention
// 512 threads, 8 waves x 16 q-rows (BM=128, BN=64), split-K=2.
// Grid 512 flat: xcd = flat&7, 4 heads per XCD (L2-resident K/V).
// Double-buffered Ks/Vs (80 KB), ONE barrier per tile; exact skip-rescale
// (alpha==1 path is bit-identical, no precision change).
__global__ __launch_bounds__(512) void k_flash(
    const u16* __restrict__ Qd, const u16* __restrict__ Kd,
    const u16* __restrict__ Vt, u16* __restrict__ OP0, u16* __restrict__ OP1,
    float* __restrict__ Mp, float* __restrict__ Lp)
{
  __shared__ __align__(16) u16 lds[40960];  // Ks0|Ks1 (2x16KB) | Vs0|Vs1 (2x16KB) | Ps 8x2KB
  const int t = threadIdx.x, lane = t & 63, wave = t >> 6;
  const int l15 = lane & 15, quad = lane >> 4;
  const int swz = (l15 & 7) << 3;

  const int flat = blockIdx.x;
  const int xcd = flat & 7, idx = flat >> 3;
  const int bh = xcd * 4 + (idx >> 4);      // 4 heads per XCD
  const int x = idx & 15;
  const int b = bh >> 4, h = bh & 15;
  const int j = x >> 1, split = x & 1;

  const size_t base  = (size_t)bh * SEQ * HD;
  const size_t baseT = (size_t)bh * HD * SEQ;
  u16* Psw = lds + 32768 + wave * 1024;     // per-wave P [16][64], swizzled
  u16* OPs = split ? OP1 : OP0;
  const int lo = 17*split, hi = lo + 17;
  const int qt0 = j, qt1 = 15 - j;
  const int len0 = 2*qt0 + 2;

  const int krow = t >> 4, kslot = t & 15;  // K stage: rows +i*32
  const int vrow = t >> 3, vslot = t & 7;   // V stage: rows +i*64

  for (int pass = 0; pass < 2; ++pass){
    const int qt = pass ? qt1 : qt0;
    const int len = 2*qt + 2;
    int kt0 = pass ? (lo - len0) : lo; if (kt0 < 0) kt0 = 0;
    int kt1 = pass ? (hi - len0) : hi; if (kt1 > len) kt1 = len;
    const int qb = qt*128 + wave*16;

    bf16x8 qf[4];
    #pragma unroll
    for (int ks = 0; ks < 4; ++ks)
      qf[ks] = *(const bf16x8*)&Qd[base + (size_t)(qb + l15)*HD + ks*32 + quad*8];

    f32x4 oacc[8] = {};
    float m_s = -1e30f, l_s = 0.f;

    if (kt0 < kt1){
      uint4 kreg[2], vreg[2];
      auto LOADT = [&](int kt){
        #pragma unroll
        for (int i = 0; i < 2; ++i){
          kreg[i] = *(const uint4*)&Kd[base + (size_t)(kt*64 + i*32 + krow)*HD + kslot*8];
          vreg[i] = *(const uint4*)&Vt[baseT + (size_t)(i*64 + vrow)*SEQ + kt*64 + vslot*8];
        }
      };
      auto WRITET = [&](int bu){
        u16* Kb = lds + bu*8192;
        u16* Vb = lds + 16384 + bu*8192;
        #pragma unroll
        for (int i = 0; i < 2; ++i){
          int kr = i*32 + krow;
          *(uint4*)&Kb[kr*128 + ((kslot*8) ^ ((kr & 7) << 3))] = kreg[i];
          int vr = i*64 + vrow;
          *(uint4*)&Vb[vr*64 + ((vslot*8) ^ ((vr & 7) << 3))] = vreg[i];
        }
      };
      LOADT(kt0);
      WRITET(0);
      if (kt0 + 1 < kt1) LOADT(kt0 + 1);
      __syncthreads();
      int buf = 0;
      for (int kt = kt0; kt < kt1; ++kt){
        if (kt*64 <= qb + 15){          // wave-uniform: tile has visible keys
          const u16* Kb = lds + buf*8192;
          const u16* Vb = lds + 16384 + buf*8192;
          f32x4 sacc[4] = {};
          #pragma unroll
          for (int ks = 0; ks < 4; ++ks){
            bf16x8 kf[4];
            #pragma unroll
            for (int nk = 0; nk < 4; ++nk)
              kf[nk] = *(const bf16x8*)&Kb[(nk*16 + l15)*128 + ((ks*32 + quad*8) ^ swz)];
            __builtin_amdgcn_s_setprio(1);
            #pragma unroll
            for (int nk = 0; nk < 4; ++nk)
              sacc[nk] = __builtin_amdgcn_mfma_f32_16x16x32_bf16(kf[nk], qf[ks], sacc[nk], 0, 0, 0);
            __builtin_amdgcn_s_setprio(0);
          }
          if (kt*64 + 63 > qb){         // diagonal tile only: apply causal mask
            int q = qb + l15;
            #pragma unroll
            for (int nk = 0; nk < 4; ++nk)
              #pragma unroll
              for (int r = 0; r < 4; ++r){
                int key = kt*64 + nk*16 + quad*4 + r;
                if (key > q) sacc[nk][r] = -1e30f;
              }
          }
          // online softmax (tree reductions, 2 cross-quad shuffles each)
          float m4[4];
          #pragma unroll
          for (int nk = 0; nk < 4; ++nk)
            m4[nk] = fmaxf(fmaxf(sacc[nk][0], sacc[nk][1]), fmaxf(sacc[nk][2], sacc[nk][3]));
          float rm = fmaxf(fmaxf(m4[0], m4[1]), fmaxf(m4[2], m4[3]));
          rm = fmaxf(rm, __shfl_xor(rm, 16));
          rm = fmaxf(rm, __shfl_xor(rm, 32));
          if (__ballot(rm > m_s) != 0){ // some row's max grew: rescale (exact skip otherwise)
            float mnew = fmaxf(m_s, rm);
            float alpha = exp2f(m_s - mnew);
            m_s = mnew;
            l_s *= alpha;
            #pragma unroll
            for (int db = 0; db < 8; ++db)
              #pragma unroll
              for (int r = 0; r < 4; ++r) oacc[db][r] *= alpha;
          }
          float s4[4];
          #pragma unroll
          for (int nk = 0; nk < 4; ++nk){
            u16 pk[4];
            float p0 = exp2f(sacc[nk][0] - m_s);
            float p1 = exp2f(sacc[nk][1] - m_s);
            float p2 = exp2f(sacc[nk][2] - m_s);
            float p3 = exp2f(sacc[nk][3] - m_s);
            pk[0] = f2b(p0); pk[1] = f2b(p1); pk[2] = f2b(p2); pk[3] = f2b(p3);
            s4[nk] = (p0 + p1) + (p2 + p3);
            *(uint2*)&Psw[l15*64 + ((nk*16 + quad*4) ^ swz)] = *(const uint2*)pk;
          }
          float rs = (s4[0] + s4[1]) + (s4[2] + s4[3]);
          rs += __shfl_xor(rs, 16);
          rs += __shfl_xor(rs, 32);
          l_s += rs;
          // O^T += V^T . P^T
          #pragma unroll
          for (int k2 = 0; k2 < 2; ++k2){
            bf16x8 pf = *(const bf16x8*)&Psw[l15*64 + ((k2*32 + quad*8) ^ swz)];
            __builtin_amdgcn_s_setprio(1);
            #pragma unroll
            for (int db = 0; db < 8; ++db){
              bf16x8 vf = *(const bf16x8*)&Vb[(db*16 + l15)*64 + ((k2*32 + quad*8) ^ swz)];
              oacc[db] = __builtin_amdgcn_mfma_f32_16x16x32_bf16(vf, pf, oacc[db], 0, 0, 0);
            }
            __builtin_amdgcn_s_setprio(0);
          }
        }
        if (kt + 1 < kt1){
          WRITET(buf ^ 1);              // vmcnt stall overlaps other waves' compute
          if (kt + 2 < kt1) LOADT(kt + 2);
          __syncthreads();              // single barrier per tile
        }
        buf ^= 1;
      }
    }
    // epilogue: O^T -> O rows via wave-PRIVATE Psw slice, 2 chunks of 64 cols
    {
      u16* Ow = Psw;                    // [16][64], swizzled
      const int qrow = lane >> 2;
      #pragma unroll
      for (int ch = 0; ch < 2; ++ch){
        #pragma unroll
        for (int db2 = 0; db2 < 4; ++db2){
          int db = ch*4 + db2;
          u16 ok[4];
          #pragma unroll
          for (int r = 0; r < 4; ++r) ok[r] = f2b(oacc[db][r]);
          *(uint2*)&Ow[l15*64 + ((db2*16 + quad*4) ^ swz)] = *(const uint2*)ok;
        }
        #pragma unroll
        for (int i = 0; i < 2; ++i){
          int c8 = (lane & 3) + i*4;
          uint4 v = *(const uint4*)&Ow[qrow*64 + ((c8*8) ^ ((qrow & 7) << 3))];
          *(uint4*)&OPs[(((size_t)(b*SEQ + qb + qrow))*NH + h)*HD + ch*64 + c8*8] = v;
        }
      }
      if (quad == 0){
        size_t mi = ((size_t)split*BSZ*NH + bh)*SEQ + (qb + l15);
        Mp[mi] = m_s;
        Lp[mi] = l_s;
      }
    }
    __syncthreads();     // pass boundary: epilogue/compute done before next stage
  }
}

// ---------------------------------------------------------------- combine splits (in-place into OP0)
__global__ __launch_bounds__(256) void k_combine(
    u16* __restrict__ OP0, const u16* __restrict__ OP1,
    const float* __restrict__ Mp, const float* __restrict__ Lp)
{
  size_t flat = ((size_t)blockIdx.x*256 + threadIdx.x)*8;
  int h = (int)((flat >> 7) & 15);
  int s = (int)((flat >> 11) & 2047);
  int b = (int)(flat >> 22);
  size_t row = ((size_t)(b*NH + h))*SEQ + s;
  const size_t off1 = (size_t)BSZ*NH*SEQ;
  float m0 = Mp[row], l0 = Lp[row];
  float m1 = Mp[row + off1], l1 = Lp[row + off1];
  float m = fmaxf(m0, m1);
  float w0 = exp2f(m0 - m), w1 = exp2f(m1 - m);
  float inv = 1.0f / (w0*l0 + w1*l1);
  uint4 a = *(const uint4*)&OP0[flat];
  uint4 c = *(const uint4*)&OP1[flat];
  const u16* pa = (const u16*)&a;
  const u16* pc = (const u16*)&c;
  u16 o[8];
  #pragma unroll
  for (int i = 0; i < 8; ++i)
    o[i] = f2b((b2f(pa[i])*w0 + b2f(pc[i])*w1) * inv);
  *(uint4*)&OP0[flat] = *(const uint4*)o;
}

// ---------------------------------------------------------------- out proj
__global__ __launch_bounds__(512, 2) void k_gemm_out(
    const u16* __restrict__ A, const u16* __restrict__ W, float* __restrict__ out)
{
  __shared__ __align__(16) u16 smem[49152];
  const int t = threadIdx.x;
  const int wg = blockIdx.x;
  const int id = (wg & 7) * 32 + (wg >> 3);   // 256 wgs, 8 XCDs, bijective
  const int tm = (id & 15) << 8;              // 16 M-tiles of 256
  const int tn = (id >> 4) << 7;              // 16 N-tiles of 128
  f32x4 acc[4][4] = {};
  gemm_core_256x128(smem, A, W, tm, tn, t, acc);
  const int lane = t & 63, l15 = lane & 15, quad = lane >> 4;
  const int wave = t >> 6, wm = wave >> 1, wn = wave & 1;
  #pragma unroll
  for (int mt = 0; mt < 4; ++mt)
    #pragma unroll
    for (int nt = 0; nt < 4; ++nt)
      #pragma unroll
      for (int r = 0; r < 4; ++r){
        int row = tm + wm*64 + mt*16 + quad*4 + r;
        int col = tn + wn*64 + nt*16 + l15;
        out[(size_t)row*DIM + col] = acc[mt][nt][r];
      }
}

// ---------------------------------------------------------------- launch
extern "C" void kernel_launch(void* const* d_in, const int* in_sizes, int n_in,
                              void* d_out, int out_size, void* d_ws, size_t ws_size,
                              hipStream_t stream)
{
  const float* x  = (const float*)d_in[0];
  const float* wq = (const float*)d_in[1];
  const float* wk = (const float*)d_in[2];
  const float* wv = (const float*)d_in[3];
  const float* wo = (const float*)d_in[4];
  const float* fc = (const float*)d_in[5];
  const float* fs = (const float*)d_in[6];
  float* out = (float*)d_out;

  char* ws = (char*)d_ws;
  u16* xb   = (u16*)(ws);                 // 16 MB  bf16 x
  u16* wqkv = (u16*)(ws + 16777216);      // 24 MB; aliased as OP1 + M/L after gemm_qkv
  u16* wob  = (u16*)(ws + 41943040);      //  8 MB
  u16* Qr   = (u16*)(ws + 50331648);      // 16 MB  (B,NH,S,HD)
  u16* Kr   = (u16*)(ws + 67108864);      // 16 MB
  u16* VtT  = (u16*)(ws + 83886080);      // 16 MB  (B,NH,HD,S) V^T, written by gemm_qkv
  u16* Ob   = (u16*)(ws + 100663296);     // 16 MB  (B,S,NH,HD): split0 partial, then combined
  u16* OP1  = wqkv;                       // 16 MB split1 partial
  float* Mp = (float*)(ws + 33554432);    // 512 KB [split][bh][s]
  float* Lp = (float*)(ws + 34078720);    // 512 KB

  k_convert <<<24576, 256, 0, stream>>>(x, wq, wk, wv, wo, xb, wqkv, wob);
  k_gemm_qkv<<<768, 512, 0, stream>>>(xb, wqkv, fc, fs, Qr, Kr, VtT);
  k_flash   <<<512, 512, 0, stream>>>(Qr, Kr, VtT, Ob, OP1, Mp, Lp);
  k_combine <<<4096, 256, 0, stream>>>(Ob, OP1, Mp, Lp);
  k_gemm_out<<<256, 512, 0, stream>>>(Ob, wob, out);
}